// Round 1
// 458.547 us; speedup vs baseline: 1.1360x; 1.1360x over previous
//
#include <hip/hip_runtime.h>

// MHFSpectralConv: rfft(16384)->256 modes->per-head complex mix->irfft + k3 conv, gated blend.
// R3: GEMM staging via global_load_lds (w=16) with XOR-swizzled LDS tiles (linear DMA dest +
// inverse-swizzled global source + swizzled ds_read) in fwd/fused; gen kernels merged;
// mix split-K reduction vectorized (float4); xpose LDS tile swizzled.

typedef __bf16 bf16x8 __attribute__((ext_vector_type(8)));
typedef __bf16 bf16x4 __attribute__((ext_vector_type(4)));
typedef float f32x4 __attribute__((ext_vector_type(4)));
typedef unsigned short ushort8v __attribute__((ext_vector_type(8)));

#define PI2_OVER_L 3.8349519697141029073e-4f  // 2*pi/16384

// async global->LDS, 16B per lane. LDS dest is wave-uniform base + lane*16 (linear);
// swizzle is realized by pre-swizzling the per-lane GLOBAL source address (rule #21).
#define GLD16(gp, lp) __builtin_amdgcn_global_load_lds( \
    (const __attribute__((address_space(1))) void*)(gp), \
    (__attribute__((address_space(3))) void*)(lp), 16, 0, 0)

// Swizzled [128][64] bf16 tile contract: physical 16B window w of row r holds logical
// window (w ^ (r&7)). DMA staging: slot s = 256*wave + 64*q + lane -> row = s>>3 (= 32w+8q+(lane>>3)),
// phys col = lane&7, so source logical col16 = (lane&7) ^ (lane>>3)  [row&7 == lane>>3].
// Fragment read of logical (row, kf..kf+8): byte = row*128 + (((kf>>3) ^ (row&7))<<4).

// ---------------- generators: F, G, conv-w convert — one launch ----------------
__global__ void gen_kern(__bf16* __restrict__ Fjt, __bf16* __restrict__ Gtj,
                         const float* __restrict__ cw, __bf16* __restrict__ wbf,
                         const float* __restrict__ gate, int fold) {
    unsigned bid = blockIdx.x;
    if (bid < 16384u) {
        // Fjt[j][t], j=2k -> cos/L ; j=2k+1 -> -sin/L. Layout [512][16384].
        unsigned idx = bid * 256u + threadIdx.x;
        unsigned k = idx >> 14, t = idx & 16383u;
        unsigned m = (k * t) & 16383u;
        float th = (float)m * PI2_OVER_L;
        float s, c;
        __sincosf(th, &s, &c);
        const float inv = 1.0f / 16384.0f;
        Fjt[((size_t)(2u * k) << 14) + t]      = (__bf16)(c * inv);
        Fjt[((size_t)(2u * k + 1u) << 14) + t] = (__bf16)(-s * inv);
    } else if (bid < 32768u) {
        // Gtj[t][j]: j=2k -> a_k cos ; j=2k+1 -> -a_k sin ; a_0=1 else 2. fold: *sigmoid(gate).
        unsigned idx = (bid - 16384u) * 256u + threadIdx.x;
        unsigned t = idx >> 8, k = idx & 255u;
        unsigned m = (k * t) & 16383u;
        float th = (float)m * PI2_OVER_L;
        float s, c;
        __sincosf(th, &s, &c);
        float a = (k == 0u) ? 1.0f : 2.0f;
        if (fold) a *= 1.0f / (1.0f + __expf(-gate[0]));
        size_t base = ((size_t)t << 9) + 2u * k;
        Gtj[base]     = (__bf16)(a * c);
        Gtj[base + 1] = (__bf16)(-a * s);
    } else {
        // conv_w (co,ci,3) fp32 -> wbf[d][co][ci] bf16. fold: *(1-sigmoid(gate)).
        int idx = (int)(bid - 32768u) * 256 + threadIdx.x;   // 49152
        float sc = 1.0f;
        if (fold) sc = 1.0f - 1.0f / (1.0f + __expf(-gate[0]));
        int co = idx / 384, r = idx - co * 384, ci = r / 3, d = r - ci * 3;
        wbf[d * 16384 + co * 128 + ci] = (__bf16)(cw[idx] * sc);
    }
}

// ---------------- transpose: x fp32 [b][ci][t] -> xTb bf16 [b][t][ci] (+ xb bf16) ----
// LDS tile [128 ci][64 t] with XOR swizzle keyed on (ci>>3)&7 so the column-gather
// (read loop: ci varies fast across lanes) spreads banks instead of 8-way colliding.
__global__ __launch_bounds__(256) void xpose_kern(const float* __restrict__ x,
        __bf16* __restrict__ xb, __bf16* __restrict__ xTb, int write_xb) {
    __shared__ __align__(16) __bf16 tile[128 * 64];
    int bid = blockIdx.x;                             // 16 b x 256 tB
    int b = bid >> 8, tB = bid & 255, t0 = tB << 6;
    int tid = threadIdx.x;
    for (int idx = tid; idx < 2048; idx += 256) {     // 128 ci x 16 float4
        int ci = idx >> 4, ch = idx & 15;
        size_t gp = ((size_t)((b << 7) + ci) << 14) + t0 + (ch << 2);
        float4 v = *(const float4*)(x + gp);
        bf16x4 p;
        p[0] = (__bf16)v.x; p[1] = (__bf16)v.y; p[2] = (__bf16)v.z; p[3] = (__bf16)v.w;
        // logical (ci, t-chunk ch*4..+4): window=ch>>1, half=ch&1, swz key=(ci>>3)&7
        *(bf16x4*)((char*)tile + (ci << 7) + (((ch >> 1) ^ ((ci >> 3) & 7)) << 4) + ((ch & 1) << 3)) = p;
        if (write_xb) *(bf16x4*)(xb + gp) = p;
    }
    __syncthreads();
    for (int idx = tid; idx < 1024; idx += 256) {     // 64 t x 16 ci-chunks
        int t = idx >> 4, ch = idx & 15;
        bf16x8 v;
#pragma unroll
        for (int j = 0; j < 8; j++) {
            int ci = (ch << 3) + j;                   // (ci>>3)&7 == ch&7 -> varies per lane
            v[j] = *(const __bf16*)((char*)tile + (ci << 7) +
                     ((((t >> 3) ^ ((ci >> 3) & 7))) << 4) + ((t & 7) << 1));
        }
        *(bf16x8*)(xTb + (((size_t)(b << 14)) + t0 + t) * 128 + ch * 8) = v;
    }
}

// ---------------- forward GEMM: C1 = x @ F (split-K), global_load_lds staging ----------------
template<int ABF>
__global__ __launch_bounds__(256) void fwd_kern(const float* __restrict__ xf,
        const __bf16* __restrict__ xbv, const __bf16* __restrict__ Fjt,
        float* __restrict__ Cp, int kchunk) {
    __shared__ __align__(16) char smem[32768];        // As [0,16K), Bs [16K,32K), swizzled
    int bid = blockIdx.x;
    int mt = bid & 15, nt = (bid >> 4) & 3, ks = bid >> 6;
    int tid = threadIdx.x, lane = tid & 63, wv = tid >> 6;
    int wm = (wv >> 1) << 6, wn = (wv & 1) << 6, lm = lane & 15;
    int rx = lm & 7;
    int r8 = lane >> 3, c8 = lane & 7;
    int srcoff = (c8 ^ r8) << 3;                      // inverse-swizzled source col (elems)
    int ldrow = (wv << 5) + r8;                       // staged row for q=0
    char* ldst = smem + (wv << 12);                   // wave-uniform LDS base
    f32x4 acc[4][4] = {};
    int k0 = ks * kchunk;
    const __bf16* ag = xbv + (((size_t)(mt * 128 + ldrow)) << 14) + k0 + srcoff;
    const __bf16* bg = Fjt + (((size_t)(nt * 128 + ldrow)) << 14) + k0 + srcoff;
    int frow = tid >> 1;
    const float* agf = xf + (((size_t)(mt * 128 + frow)) << 14) + k0;
    for (int kk = 0; kk < kchunk; kk += 64) {
        if (ABF) {
#pragma unroll
            for (int q = 0; q < 4; q++)
                GLD16(ag + (((size_t)q) << 17) + kk, ldst + (q << 10));
        } else {
            // fp32 path: reg-staged convert, written to the same swizzled layout
#pragma unroll
            for (int q = 0; q < 4; q++) {
                int sl = ((tid & 1) << 2) + q;
                const float4* p = (const float4*)(agf + kk + (sl << 3));
                float4 v0 = p[0], v1 = p[1];
                bf16x8 t;
                t[0] = (__bf16)v0.x; t[1] = (__bf16)v0.y; t[2] = (__bf16)v0.z; t[3] = (__bf16)v0.w;
                t[4] = (__bf16)v1.x; t[5] = (__bf16)v1.y; t[6] = (__bf16)v1.z; t[7] = (__bf16)v1.w;
                *(bf16x8*)(smem + (frow << 7) + ((sl ^ (frow & 7)) << 4)) = t;
            }
        }
#pragma unroll
        for (int q = 0; q < 4; q++)
            GLD16(bg + (((size_t)q) << 17) + kk, ldst + 16384 + (q << 10));
        __syncthreads();
#pragma unroll
        for (int ks2 = 0; ks2 < 64; ks2 += 32) {
            int wb = (ks2 >> 3) + (lane >> 4);
            int wa = (wb ^ rx) << 4;
            bf16x8 af[4], bfv[4];
#pragma unroll
            for (int i = 0; i < 4; i++)
                af[i] = *(const bf16x8*)(smem + ((wm + i * 16 + lm) << 7) + wa);
#pragma unroll
            for (int j = 0; j < 4; j++)
                bfv[j] = *(const bf16x8*)(smem + 16384 + ((wn + j * 16 + lm) << 7) + wa);
#pragma unroll
            for (int i = 0; i < 4; i++)
#pragma unroll
                for (int j = 0; j < 4; j++)
                    acc[i][j] = __builtin_amdgcn_mfma_f32_16x16x32_bf16(af[i], bfv[j], acc[i][j], 0, 0, 0);
        }
        __syncthreads();
    }
    float* outp = Cp + (size_t)ks * (2048 * 512);
    int q = lane >> 4, cl = lane & 15;
#pragma unroll
    for (int i = 0; i < 4; i++)
#pragma unroll
        for (int j = 0; j < 4; j++) {
            int col = nt * 128 + wn + j * 16 + cl;
#pragma unroll
            for (int r = 0; r < 4; r++) {
                int row = mt * 128 + wm + i * 16 + q * 4 + r;
                outp[(size_t)row * 512 + col] = acc[i][j][r];
            }
        }
}

// ---------------- mixing: O = sum_i F * w (complex). grid 256 = 128 bh x 2 k-halves ---------
__global__ __launch_bounds__(256) void mix_kern(const float* __restrict__ Cp,
        const float* __restrict__ wre, const float* __restrict__ wim,
        __bf16* __restrict__ Ob, int ns) {
    __shared__ __align__(16) float Fs[16 * 256];
    int bid = blockIdx.x, bh = bid >> 1, kh = bid & 1;
    int b = bh >> 3, h = bh & 7;
    int tid = threadIdx.x;
    size_t base = (size_t)(b * 128 + h * 16) * 512 + kh * 256;
    for (int idx = tid; idx < 1024; idx += 256) {     // 1024 float4 = 4096 floats
        int i = idx >> 6, jj = (idx & 63) << 2;
        const float* p = Cp + base + (size_t)i * 512 + jj;
        f32x4 v = {};
#pragma unroll 4
        for (int s = 0; s < ns; s++) v += *(const f32x4*)(p + (size_t)s * 1048576);
        *(f32x4*)&Fs[i * 256 + jj] = v;
    }
    __syncthreads();
    for (int idx = tid; idx < 2048; idx += 256) {
        int o = idx >> 7, kl = idx & 127;
        int k = kh * 128 + kl;
        float ar = 0.f, ai = 0.f;
        const float* wr0 = wre + ((size_t)(h * 256 + o) << 8) + k;
        const float* wi0 = wim + ((size_t)(h * 256 + o) << 8) + k;
#pragma unroll 4
        for (int i = 0; i < 16; i++) {
            float fr = Fs[i * 256 + 2 * kl], fi = Fs[i * 256 + 2 * kl + 1];
            float wr = wr0[(size_t)i * 4096], wi = wi0[(size_t)i * 4096];
            ar += fr * wr - fi * wi;
            ai += fr * wi + fi * wr;
        }
        size_t ro = (size_t)(b * 128 + h * 16 + o) * 512;
        Ob[ro + 2 * k]     = (__bf16)ar;
        Ob[ro + 2 * k + 1] = (__bf16)ai;
    }
}

// ---------------- fused inverse + conv: out = Ob@(g*G) + ((1-g)*W)*xT + blended bias --------
__global__ __launch_bounds__(256) void fused_kern(const __bf16* __restrict__ Ob,
        const __bf16* __restrict__ Gtj, const __bf16* __restrict__ wbf,
        const __bf16* __restrict__ xTb, const float* __restrict__ bias,
        const float* __restrict__ cb, const float* __restrict__ gate,
        float* __restrict__ out) {
    __shared__ __align__(16) char smem[33024];        // [0,16K): As/Ws ; [16K,33024): Bs/xT(130 rows)
    int bid = blockIdx.x, b = bid & 15, tt = bid >> 4;   // 16 b x 128 t-tiles
    int t0 = tt << 7;
    int tid = threadIdx.x, lane = tid & 63, wv = tid >> 6;
    int wm = (wv >> 1) << 6, wn = (wv & 1) << 6, lm = lane & 15;
    int rx = lm & 7;
    int r8 = lane >> 3, c8 = lane & 7;
    int srcoff = (c8 ^ r8) << 3;
    int ldrow = (wv << 5) + r8;
    char* ldst = smem + (wv << 12);
    f32x4 acc[4][4] = {};

    // ---- spectral phase: K=512 over Ob rows (m=co) x Gtj rows (n=t) ----
    {
        const __bf16* ag = Ob  + ((size_t)(b  * 128 + ldrow) << 9) + srcoff;
        const __bf16* bg = Gtj + ((size_t)(tt * 128 + ldrow) << 9) + srcoff;
        for (int k0 = 0; k0 < 512; k0 += 64) {
#pragma unroll
            for (int q = 0; q < 4; q++) {
                GLD16(ag + ((size_t)q << 12) + k0, ldst + (q << 10));
                GLD16(bg + ((size_t)q << 12) + k0, ldst + 16384 + (q << 10));
            }
            __syncthreads();
#pragma unroll
            for (int ks2 = 0; ks2 < 64; ks2 += 32) {
                int wb = (ks2 >> 3) + (lane >> 4);
                int wa = (wb ^ rx) << 4;
                bf16x8 af[4], bfv[4];
#pragma unroll
                for (int i = 0; i < 4; i++)
                    af[i] = *(const bf16x8*)(smem + ((wm + i * 16 + lm) << 7) + wa);
#pragma unroll
                for (int j = 0; j < 4; j++)
                    bfv[j] = *(const bf16x8*)(smem + 16384 + ((wn + j * 16 + lm) << 7) + wa);
#pragma unroll
                for (int i = 0; i < 4; i++)
#pragma unroll
                    for (int j = 0; j < 4; j++)
                        acc[i][j] = __builtin_amdgcn_mfma_f32_16x16x32_bf16(af[i], bfv[j], acc[i][j], 0, 0, 0);
            }
            __syncthreads();
        }
    }

    // ---- conv phase: K = 3 taps x 128 ci (ci chunked by 64) ----
    {
        char* xT = smem + 16384;                      // [130][64] swizzled, 16640 B
        for (int c0p = 0; c0p < 2; c0p++) {
            int c0 = c0p << 6;
            if (c0p) __syncthreads();                 // prior MFMA done before xT overwrite
            for (int idx = tid; idx < 1040; idx += 256) {   // 130 rows x 8 chunks (reg-staged: halo mask)
                int row = idx >> 3, ch = idx & 7;
                int tg = t0 - 1 + row;
                ushort8v v = {};
                if (tg >= 0 && tg < 16384)
                    v = *(const ushort8v*)(xTb + ((((size_t)(b << 14)) + tg) << 7) + c0 + (ch << 3));
                *(ushort8v*)(xT + (row << 7) + ((ch ^ (row & 7)) << 4)) = v;
            }
            const __bf16* wg = wbf + (ldrow << 7) + c0 + srcoff;
            for (int d = 0; d < 3; d++) {
                if (d) __syncthreads();               // prior MFMA done before Ws overwrite
#pragma unroll
                for (int q = 0; q < 4; q++)
                    GLD16(wg + d * 16384 + (q << 10), ldst + (q << 10));
                __syncthreads();
#pragma unroll
                for (int ks2 = 0; ks2 < 64; ks2 += 32) {
                    int wb = (ks2 >> 3) + (lane >> 4);
                    int wa = (wb ^ rx) << 4;
                    bf16x8 af[4], bfv[4];
#pragma unroll
                    for (int i = 0; i < 4; i++)
                        af[i] = *(const bf16x8*)(smem + ((wm + i * 16 + lm) << 7) + wa);
#pragma unroll
                    for (int j = 0; j < 4; j++) {
                        int r2 = wn + j * 16 + lm + d;
                        bfv[j] = *(const bf16x8*)(xT + (r2 << 7) + ((wb ^ (r2 & 7)) << 4));
                    }
#pragma unroll
                    for (int i = 0; i < 4; i++)
#pragma unroll
                        for (int j = 0; j < 4; j++)
                            acc[i][j] = __builtin_amdgcn_mfma_f32_16x16x32_bf16(af[i], bfv[j], acc[i][j], 0, 0, 0);
                }
            }
        }
    }

    // ---- epilogue: blended bias, write-only out ----
    float g = 1.0f / (1.0f + __expf(-gate[0]));
    int q = lane >> 4, cl = lane & 15;
#pragma unroll
    for (int i = 0; i < 4; i++)
#pragma unroll
        for (int j = 0; j < 4; j++) {
            int t = t0 + wn + j * 16 + cl;
#pragma unroll
            for (int r = 0; r < 4; r++) {
                int co = wm + i * 16 + q * 4 + r;
                float gb = g * bias[co] + (1.0f - g) * cb[co];
                out[((size_t)(b * 128 + co) << 14) + t] = acc[i][j][r] + gb;
            }
        }
}

// ---------------- fallback (low-ws) conv + inv, round-1 versions ----------------
#define SA 72
#define SXC 40
__global__ __launch_bounds__(256) void conv_kern(const float* __restrict__ x,
        const __bf16* __restrict__ wbf, const float* __restrict__ cb,
        float* __restrict__ out) {
    __shared__ __align__(16) __bf16 xT[130 * SXC];
    __shared__ __align__(16) __bf16 wS[3 * 128 * SXC];
    int bid = blockIdx.x, b = bid >> 7, t0 = (bid & 127) << 7;
    int tid = threadIdx.x, lane = tid & 63, wv = tid >> 6;
    int wm = (wv >> 1) << 6, wn = (wv & 1) << 6;
    f32x4 acc[4][4] = {};
    for (int c0 = 0; c0 < 128; c0 += 32) {
        for (int idx = tid; idx < 1536; idx += 256) {
            int d = idx / 512, rem = idx - d * 512, co = rem >> 2, g = rem & 3;
            ushort8v v = *(const ushort8v*)(wbf + d * 16384 + co * 128 + c0 + g * 8);
            *(ushort8v*)&wS[d * (128 * SXC) + co * SXC + g * 8] = v;
        }
        for (int idx = tid; idx < 4160; idx += 256) {
            int cc = idx / 130, tl = idx - cc * 130;
            int tg = t0 + tl - 1;
            float v = 0.f;
            if (tg >= 0 && tg < 16384)
                v = x[((size_t)(b * 128 + c0 + cc) << 14) + tg];
            xT[tl * SXC + cc] = (__bf16)v;
        }
        __syncthreads();
        int kf = (lane >> 4) << 3;
#pragma unroll
        for (int d = 0; d < 3; d++) {
            bf16x8 af[4], bfv[4];
#pragma unroll
            for (int i = 0; i < 4; i++)
                af[i] = *(const bf16x8*)&wS[d * (128 * SXC) + (wm + i * 16 + (lane & 15)) * SXC + kf];
#pragma unroll
            for (int j = 0; j < 4; j++)
                bfv[j] = *(const bf16x8*)&xT[(wn + j * 16 + (lane & 15) + d) * SXC + kf];
#pragma unroll
            for (int i = 0; i < 4; i++)
#pragma unroll
                for (int j = 0; j < 4; j++)
                    acc[i][j] = __builtin_amdgcn_mfma_f32_16x16x32_bf16(af[i], bfv[j], acc[i][j], 0, 0, 0);
        }
        __syncthreads();
    }
    int q = lane >> 4, cl = lane & 15;
#pragma unroll
    for (int i = 0; i < 4; i++)
#pragma unroll
        for (int j = 0; j < 4; j++) {
            int t = t0 + wn + j * 16 + cl;
#pragma unroll
            for (int r = 0; r < 4; r++) {
                int co = wm + i * 16 + q * 4 + r;
                out[((size_t)(b * 128 + co) << 14) + t] = acc[i][j][r] + cb[co];
            }
        }
}

__global__ __launch_bounds__(256) void inv_kern(const __bf16* __restrict__ Ob,
        const __bf16* __restrict__ Gtj, const float* __restrict__ bias,
        const float* __restrict__ gate, float* __restrict__ out) {
    __shared__ __align__(16) __bf16 As[128 * SA];
    __shared__ __align__(16) __bf16 Bs[128 * SA];
    int bid = blockIdx.x, mt = bid & 15, tt = bid >> 4;
    int tid = threadIdx.x, lane = tid & 63, wv = tid >> 6;
    int wm = (wv >> 1) << 6, wn = (wv & 1) << 6;
    f32x4 acc[4][4] = {};
    int arow = tid >> 1, ahalf = (tid & 1) << 5;
    const __bf16* ag = Ob  + (size_t)(mt * 128 + arow) * 512 + ahalf;
    const __bf16* bg = Gtj + (size_t)(tt * 128 + arow) * 512 + ahalf;
    __bf16* ad = &As[arow * SA + ahalf];
    __bf16* bd = &Bs[arow * SA + ahalf];
    for (int k0 = 0; k0 < 512; k0 += 64) {
#pragma unroll
        for (int q = 0; q < 4; q++) {
            ((ushort8v*)ad)[q] = ((const ushort8v*)(ag + k0))[q];
            ((ushort8v*)bd)[q] = ((const ushort8v*)(bg + k0))[q];
        }
        __syncthreads();
#pragma unroll
        for (int ks2 = 0; ks2 < 64; ks2 += 32) {
            int kf = ks2 + ((lane >> 4) << 3);
            bf16x8 af[4], bfv[4];
#pragma unroll
            for (int i = 0; i < 4; i++)
                af[i] = *(const bf16x8*)&As[(wm + i * 16 + (lane & 15)) * SA + kf];
#pragma unroll
            for (int j = 0; j < 4; j++)
                bfv[j] = *(const bf16x8*)&Bs[(wn + j * 16 + (lane & 15)) * SA + kf];
#pragma unroll
            for (int i = 0; i < 4; i++)
#pragma unroll
                for (int j = 0; j < 4; j++)
                    acc[i][j] = __builtin_amdgcn_mfma_f32_16x16x32_bf16(af[i], bfv[j], acc[i][j], 0, 0, 0);
        }
        __syncthreads();
    }
    float g = 1.0f / (1.0f + __expf(-gate[0]));
    float gi = 1.0f - g;
    int q = lane >> 4, cl = lane & 15;
#pragma unroll
    for (int i = 0; i < 4; i++)
#pragma unroll
        for (int j = 0; j < 4; j++) {
            int col = (tt << 7) + wn + j * 16 + cl;
#pragma unroll
            for (int r = 0; r < 4; r++) {
                int row = mt * 128 + wm + i * 16 + q * 4 + r;
                size_t oi = ((size_t)row << 14) + col;
                out[oi] = g * (acc[i][j][r] + bias[row & 127]) + gi * out[oi];
            }
        }
}

extern "C" void kernel_launch(void* const* d_in, const int* in_sizes, int n_in,
                              void* d_out, int out_size, void* d_ws, size_t ws_size,
                              hipStream_t stream) {
    const float* x    = (const float*)d_in[0];
    const float* wre  = (const float*)d_in[1];
    const float* wim  = (const float*)d_in[2];
    const float* bias = (const float*)d_in[3];
    const float* cw   = (const float*)d_in[4];
    const float* cb   = (const float*)d_in[5];
    const float* gate = (const float*)d_in[6];
    float* out = (float*)d_out;
    char* ws = (char*)d_ws;

    const size_t SZ_F = 16777216, SZ_G = 16777216, SZ_W = 98304;
    const size_t SZ_X = 67108864, SZ_CP8 = 33554432, SZ_CP4 = 16777216, SZ_OB = 2097152;
    size_t oG = SZ_F, oW = oG + SZ_G, oEnd = oW + SZ_W;   // 33,652,736

    size_t needT3 = oEnd + 2 * SZ_X + SZ_CP8 + SZ_OB;     // 203,522,048
    size_t needT2 = oEnd + SZ_X + SZ_CP8 + SZ_OB;         // 136,413,184
    size_t needT1 = oEnd + SZ_X + SZ_CP4 + SZ_OB;         // 119,635,968

    __bf16* Fjt = (__bf16*)(ws);
    __bf16* Gtj = (__bf16*)(ws + oG);
    __bf16* wbf = (__bf16*)(ws + oW);

    if (ws_size >= needT1) {
        // fused path
        int use_xb = (ws_size >= needT3);
        int ns = (ws_size >= needT2) ? 8 : 4;
        __bf16* xb  = use_xb ? (__bf16*)(ws + oEnd) : nullptr;
        __bf16* xTb = (__bf16*)(ws + oEnd + (use_xb ? SZ_X : 0));
        float*  Cp  = (float*)((char*)xTb + SZ_X);
        __bf16* Ob  = (__bf16*)((char*)Cp + (size_t)ns * 4194304);
        int kchunk = 16384 / ns;

        gen_kern<<<32960, 256, 0, stream>>>(Fjt, Gtj, cw, wbf, gate, 1);
        xpose_kern<<<4096, 256, 0, stream>>>(x, xb, xTb, use_xb);
        if (use_xb)
            fwd_kern<1><<<64 * ns, 256, 0, stream>>>(x, xb, Fjt, Cp, kchunk);
        else
            fwd_kern<0><<<64 * ns, 256, 0, stream>>>(x, nullptr, Fjt, Cp, kchunk);
        mix_kern<<<256, 256, 0, stream>>>(Cp, wre, wim, Ob, ns);
        fused_kern<<<2048, 256, 0, stream>>>(Ob, Gtj, wbf, xTb, bias, cb, gate, out);
    } else {
        // round-1 fallback path
        float*  Cp  = (float*)(ws + oEnd);
        size_t need8 = oEnd + 8ull * 4194304ull + SZ_OB;
        int ns = (ws_size >= need8) ? 8 : 4;
        __bf16* Ob  = (__bf16*)(ws + oEnd + (size_t)ns * 4194304);
        int kchunk = 16384 / ns;

        gen_kern<<<32960, 256, 0, stream>>>(Fjt, Gtj, cw, wbf, gate, 0);
        fwd_kern<0><<<64 * ns, 256, 0, stream>>>(x, nullptr, Fjt, Cp, kchunk);
        mix_kern<<<256, 256, 0, stream>>>(Cp, wre, wim, Ob, ns);
        conv_kern<<<2048, 256, 0, stream>>>(x, wbf, cb, out);
        inv_kern<<<2048, 256, 0, stream>>>(Ob, Gtj, bias, gate, out);
    }
}

// Round 2
// 427.817 us; speedup vs baseline: 1.2176x; 1.0718x over previous
//
#include <hip/hip_runtime.h>

// MHFSpectralConv: rfft(16384)->256 modes->per-head complex mix->irfft + k3 conv, gated blend.
// R4: 2-phase double-buffered pipeline (stage k+1 while MFMA k; one barrier/step) in fused_kern
// and fwd_kern<1>; conv phase folded into the dbuf chain with GLD16-staged xT (halo via 16-lane
// reg-stage); fwd bid remap for split-K XCD/L2 affinity. Swizzle contract unchanged from R3.

typedef __bf16 bf16x8 __attribute__((ext_vector_type(8)));
typedef __bf16 bf16x4 __attribute__((ext_vector_type(4)));
typedef float f32x4 __attribute__((ext_vector_type(4)));
typedef unsigned short ushort8v __attribute__((ext_vector_type(8)));

#define PI2_OVER_L 3.8349519697141029073e-4f  // 2*pi/16384

// async global->LDS, 16B per lane. LDS dest is wave-uniform base + lane*16 (linear);
// swizzle is realized by pre-swizzling the per-lane GLOBAL source address (rule #21).
#define GLD16(gp, lp) __builtin_amdgcn_global_load_lds( \
    (const __attribute__((address_space(1))) void*)(gp), \
    (__attribute__((address_space(3))) void*)(lp), 16, 0, 0)

// Swizzled [R][64] bf16 tile contract: physical 16B window w of row r holds logical
// window (w ^ (r&7)). DMA staging: per wave-call, row = base_row + (lane>>3), phys col16 =
// lane&7, so global source col16 = (lane&7) ^ (row&7). Fragment read of logical (row, w):
// byte = row*128 + ((w ^ (row&7))<<4).

// ---------------- generators: F, G, conv-w convert — one launch ----------------
__global__ void gen_kern(__bf16* __restrict__ Fjt, __bf16* __restrict__ Gtj,
                         const float* __restrict__ cw, __bf16* __restrict__ wbf,
                         const float* __restrict__ gate, int fold) {
    unsigned bid = blockIdx.x;
    if (bid < 16384u) {
        // Fjt[j][t], j=2k -> cos/L ; j=2k+1 -> -sin/L. Layout [512][16384].
        unsigned idx = bid * 256u + threadIdx.x;
        unsigned k = idx >> 14, t = idx & 16383u;
        unsigned m = (k * t) & 16383u;
        float th = (float)m * PI2_OVER_L;
        float s, c;
        __sincosf(th, &s, &c);
        const float inv = 1.0f / 16384.0f;
        Fjt[((size_t)(2u * k) << 14) + t]      = (__bf16)(c * inv);
        Fjt[((size_t)(2u * k + 1u) << 14) + t] = (__bf16)(-s * inv);
    } else if (bid < 32768u) {
        // Gtj[t][j]: j=2k -> a_k cos ; j=2k+1 -> -a_k sin ; a_0=1 else 2. fold: *sigmoid(gate).
        unsigned idx = (bid - 16384u) * 256u + threadIdx.x;
        unsigned t = idx >> 8, k = idx & 255u;
        unsigned m = (k * t) & 16383u;
        float th = (float)m * PI2_OVER_L;
        float s, c;
        __sincosf(th, &s, &c);
        float a = (k == 0u) ? 1.0f : 2.0f;
        if (fold) a *= 1.0f / (1.0f + __expf(-gate[0]));
        size_t base = ((size_t)t << 9) + 2u * k;
        Gtj[base]     = (__bf16)(a * c);
        Gtj[base + 1] = (__bf16)(-a * s);
    } else {
        // conv_w (co,ci,3) fp32 -> wbf[d][co][ci] bf16. fold: *(1-sigmoid(gate)).
        int idx = (int)(bid - 32768u) * 256 + threadIdx.x;   // 49152
        float sc = 1.0f;
        if (fold) sc = 1.0f - 1.0f / (1.0f + __expf(-gate[0]));
        int co = idx / 384, r = idx - co * 384, ci = r / 3, d = r - ci * 3;
        wbf[d * 16384 + co * 128 + ci] = (__bf16)(cw[idx] * sc);
    }
}

// ---------------- transpose: x fp32 [b][ci][t] -> xTb bf16 [b][t][ci] (+ xb bf16) ----
__global__ __launch_bounds__(256) void xpose_kern(const float* __restrict__ x,
        __bf16* __restrict__ xb, __bf16* __restrict__ xTb, int write_xb) {
    __shared__ __align__(16) __bf16 tile[128 * 64];
    int bid = blockIdx.x;                             // 16 b x 256 tB
    int b = bid >> 8, tB = bid & 255, t0 = tB << 6;
    int tid = threadIdx.x;
    for (int idx = tid; idx < 2048; idx += 256) {     // 128 ci x 16 float4
        int ci = idx >> 4, ch = idx & 15;
        size_t gp = ((size_t)((b << 7) + ci) << 14) + t0 + (ch << 2);
        float4 v = *(const float4*)(x + gp);
        bf16x4 p;
        p[0] = (__bf16)v.x; p[1] = (__bf16)v.y; p[2] = (__bf16)v.z; p[3] = (__bf16)v.w;
        *(bf16x4*)((char*)tile + (ci << 7) + (((ch >> 1) ^ ((ci >> 3) & 7)) << 4) + ((ch & 1) << 3)) = p;
        if (write_xb) *(bf16x4*)(xb + gp) = p;
    }
    __syncthreads();
    for (int idx = tid; idx < 1024; idx += 256) {     // 64 t x 16 ci-chunks
        int t = idx >> 4, ch = idx & 15;
        bf16x8 v;
#pragma unroll
        for (int j = 0; j < 8; j++) {
            int ci = (ch << 3) + j;
            v[j] = *(const __bf16*)((char*)tile + (ci << 7) +
                     ((((t >> 3) ^ ((ci >> 3) & 7))) << 4) + ((t & 7) << 1));
        }
        *(bf16x8*)(xTb + (((size_t)(b << 14)) + t0 + t) * 128 + ch * 8) = v;
    }
}

// ---------------- forward GEMM: C1 = x @ F (split-K), 2-phase dbuf ----------------
template<int ABF>
__global__ __launch_bounds__(256) void fwd_kern(const float* __restrict__ xf,
        const __bf16* __restrict__ xbv, const __bf16* __restrict__ Fjt,
        float* __restrict__ Cp, int kchunk) {
    extern __shared__ __align__(16) char smem[];
    int bid = blockIdx.x;
    // bid remap: ks fastest (XCD = bid%8 owns one split-K slice), nt next, mt slowest ->
    // A/B panel sharers are same-XCD adjacent.
    int ks, mt, nt;
    if (kchunk == 2048) { ks = bid & 7; nt = (bid >> 3) & 3; mt = bid >> 5; }
    else               { ks = bid & 3; nt = (bid >> 2) & 3; mt = bid >> 4; }
    int tid = threadIdx.x, lane = tid & 63, wv = tid >> 6;
    int wm = (wv >> 1) << 6, wn = (wv & 1) << 6, lm = lane & 15;
    int rx = lm & 7;
    int r8 = lane >> 3, c8 = lane & 7;
    int srcoff = (c8 ^ r8) << 3;
    int ldrow = (wv << 5) + r8;
    f32x4 acc[4][4] = {};
    int k0 = ks * kchunk;
    const __bf16* ag = xbv + (((size_t)(mt * 128 + ldrow)) << 14) + k0 + srcoff;
    const __bf16* bg = Fjt + (((size_t)(nt * 128 + ldrow)) << 14) + k0 + srcoff;

    char* A0 = smem;          char* B0 = smem + 16384;
    char* A1 = smem + 32768;  char* B1 = smem + 49152;

    auto COMPUTE = [&](const char* A, const char* B) {
#pragma unroll
        for (int ks2 = 0; ks2 < 64; ks2 += 32) {
            int wb = (ks2 >> 3) + (lane >> 4);
            int wa = (wb ^ rx) << 4;
            bf16x8 af[4], bfv[4];
#pragma unroll
            for (int i = 0; i < 4; i++)
                af[i] = *(const bf16x8*)(A + ((wm + i * 16 + lm) << 7) + wa);
#pragma unroll
            for (int j = 0; j < 4; j++)
                bfv[j] = *(const bf16x8*)(B + ((wn + j * 16 + lm) << 7) + wa);
#pragma unroll
            for (int i = 0; i < 4; i++)
#pragma unroll
                for (int j = 0; j < 4; j++)
                    acc[i][j] = __builtin_amdgcn_mfma_f32_16x16x32_bf16(af[i], bfv[j], acc[i][j], 0, 0, 0);
        }
    };

    if (ABF) {
        auto STAGE = [&](char* A, char* B, int kk) {
#pragma unroll
            for (int q = 0; q < 4; q++) {
                GLD16(ag + (((size_t)q) << 17) + kk, A + (wv << 12) + (q << 10));
                GLD16(bg + (((size_t)q) << 17) + kk, B + (wv << 12) + (q << 10));
            }
        };
        STAGE(A0, B0, 0);
        __syncthreads();
        for (int kk = 0; kk < kchunk; kk += 128) {
            STAGE(A1, B1, kk + 64);
            COMPUTE(A0, B0);
            __syncthreads();
            if (kk + 128 < kchunk) STAGE(A0, B0, kk + 128);
            COMPUTE(A1, B1);
            __syncthreads();
        }
    } else {
        // fp32 path: reg-staged convert (single-buffer, round-3 structure)
        int frow = tid >> 1;
        const float* agf = xf + (((size_t)(mt * 128 + frow)) << 14) + k0;
        for (int kk = 0; kk < kchunk; kk += 64) {
#pragma unroll
            for (int q = 0; q < 4; q++) {
                int sl = ((tid & 1) << 2) + q;
                const float4* p = (const float4*)(agf + kk + (sl << 3));
                float4 v0 = p[0], v1 = p[1];
                bf16x8 t;
                t[0] = (__bf16)v0.x; t[1] = (__bf16)v0.y; t[2] = (__bf16)v0.z; t[3] = (__bf16)v0.w;
                t[4] = (__bf16)v1.x; t[5] = (__bf16)v1.y; t[6] = (__bf16)v1.z; t[7] = (__bf16)v1.w;
                *(bf16x8*)(A0 + (frow << 7) + ((sl ^ (frow & 7)) << 4)) = t;
            }
#pragma unroll
            for (int q = 0; q < 4; q++)
                GLD16(bg + (((size_t)q) << 17) + kk, B0 + (wv << 12) + (q << 10));
            __syncthreads();
            COMPUTE(A0, B0);
            __syncthreads();
        }
    }

    float* outp = Cp + (size_t)ks * (2048 * 512);
    int q = lane >> 4, cl = lane & 15;
#pragma unroll
    for (int i = 0; i < 4; i++)
#pragma unroll
        for (int j = 0; j < 4; j++) {
            int col = nt * 128 + wn + j * 16 + cl;
#pragma unroll
            for (int r = 0; r < 4; r++) {
                int row = mt * 128 + wm + i * 16 + q * 4 + r;
                outp[(size_t)row * 512 + col] = acc[i][j][r];
            }
        }
}

// ---------------- mixing: O = sum_i F * w (complex). grid 256 = 128 bh x 2 k-halves ---------
__global__ __launch_bounds__(256) void mix_kern(const float* __restrict__ Cp,
        const float* __restrict__ wre, const float* __restrict__ wim,
        __bf16* __restrict__ Ob, int ns) {
    __shared__ __align__(16) float Fs[16 * 256];
    int bid = blockIdx.x, bh = bid >> 1, kh = bid & 1;
    int b = bh >> 3, h = bh & 7;
    int tid = threadIdx.x;
    size_t base = (size_t)(b * 128 + h * 16) * 512 + kh * 256;
    for (int idx = tid; idx < 1024; idx += 256) {
        int i = idx >> 6, jj = (idx & 63) << 2;
        const float* p = Cp + base + (size_t)i * 512 + jj;
        f32x4 v = {};
#pragma unroll 4
        for (int s = 0; s < ns; s++) v += *(const f32x4*)(p + (size_t)s * 1048576);
        *(f32x4*)&Fs[i * 256 + jj] = v;
    }
    __syncthreads();
    for (int idx = tid; idx < 2048; idx += 256) {
        int o = idx >> 7, kl = idx & 127;
        int k = kh * 128 + kl;
        float ar = 0.f, ai = 0.f;
        const float* wr0 = wre + ((size_t)(h * 256 + o) << 8) + k;
        const float* wi0 = wim + ((size_t)(h * 256 + o) << 8) + k;
#pragma unroll 4
        for (int i = 0; i < 16; i++) {
            float fr = Fs[i * 256 + 2 * kl], fi = Fs[i * 256 + 2 * kl + 1];
            float wr = wr0[(size_t)i * 4096], wi = wi0[(size_t)i * 4096];
            ar += fr * wr - fi * wi;
            ai += fr * wi + fi * wr;
        }
        size_t ro = (size_t)(b * 128 + h * 16 + o) * 512;
        Ob[ro + 2 * k]     = (__bf16)ar;
        Ob[ro + 2 * k + 1] = (__bf16)ai;
    }
}

// ---------------- fused inverse + conv: out = Ob@(g*G) + ((1-g)*W)*xT + blended bias --------
// 2-phase dbuf: 4 buffers of 16640 B (130 rows x 128 B). Spectral: 8 k-steps; conv
// prefetch overlaps last spectral step; 6 conv steps each stage the next Ws tile.
__global__ __launch_bounds__(256) void fused_kern(const __bf16* __restrict__ Ob,
        const __bf16* __restrict__ Gtj, const __bf16* __restrict__ wbf,
        const __bf16* __restrict__ xTb, const float* __restrict__ bias,
        const float* __restrict__ cb, const float* __restrict__ gate,
        float* __restrict__ out) {
    extern __shared__ __align__(16) char smem[];      // 66560 B
    int bid = blockIdx.x, b = bid & 15, tt = bid >> 4;   // 16 b x 128 t-tiles
    int t0 = tt << 7;
    int tid = threadIdx.x, lane = tid & 63, wv = tid >> 6;
    int wm = (wv >> 1) << 6, wn = (wv & 1) << 6, lm = lane & 15;
    int rx = lm & 7;
    int r8 = lane >> 3, c8 = lane & 7;
    int srcoff = (c8 ^ r8) << 3;
    int ldrow = (wv << 5) + r8;
    f32x4 acc[4][4] = {};

    char* A0 = smem;          char* B0 = smem + 16640;
    char* A1 = smem + 33280;  char* B1 = smem + 49920;

    const __bf16* ag = Ob  + ((size_t)(b  * 128 + ldrow) << 9) + srcoff;
    const __bf16* bg = Gtj + ((size_t)(tt * 128 + ldrow) << 9) + srcoff;
    const __bf16* wg = wbf + (ldrow << 7) + srcoff;
    // xT main rows: buffer row r=1..128 <-> t = t0 + r - 1; key (r&7) = (1+r8)&7
    const __bf16* xg = xTb + ((((size_t)(b << 14)) + t0 + (wv << 5) + r8) << 7)
                           + ((c8 ^ ((1 + r8) & 7)) << 3);

    auto STAGE_AB = [&](char* A, char* B, int kk) {
#pragma unroll
        for (int q = 0; q < 4; q++) {
            GLD16(ag + ((size_t)q << 12) + kk, A + (wv << 12) + (q << 10));
            GLD16(bg + ((size_t)q << 12) + kk, B + (wv << 12) + (q << 10));
        }
    };
    auto STAGE_W = [&](char* A, int d, int c0) {
#pragma unroll
        for (int q = 0; q < 4; q++)
            GLD16(wg + d * 16384 + c0 + (q << 10), A + (wv << 12) + (q << 10));
    };
    auto STAGE_X = [&](char* X, int c0) {             // rows 1..128 (always in-bounds)
#pragma unroll
        for (int q = 0; q < 4; q++)
            GLD16(xg + c0 + (q << 10), X + 128 + (wv << 12) + (q << 10));
    };
    auto EDGE_X = [&](char* X, int c0) {              // rows 0 (t0-1) and 129 (t0+128)
        if (tid < 16) {
            int rr = (tid >> 3) ? 129 : 0;
            int ch = tid & 7;
            int tg = t0 - 1 + rr;
            ushort8v v = {};
            if (tg >= 0 && tg < 16384)
                v = *(const ushort8v*)(xTb + (((size_t)(b << 14)) + tg) * 128 + c0 + ch * 8);
            *(ushort8v*)(X + (rr << 7) + ((ch ^ (rr & 7)) << 4)) = v;
        }
    };
    auto SPECC = [&](const char* A, const char* B) {
#pragma unroll
        for (int ks2 = 0; ks2 < 64; ks2 += 32) {
            int wb = (ks2 >> 3) + (lane >> 4);
            int wa = (wb ^ rx) << 4;
            bf16x8 af[4], bfv[4];
#pragma unroll
            for (int i = 0; i < 4; i++)
                af[i] = *(const bf16x8*)(A + ((wm + i * 16 + lm) << 7) + wa);
#pragma unroll
            for (int j = 0; j < 4; j++)
                bfv[j] = *(const bf16x8*)(B + ((wn + j * 16 + lm) << 7) + wa);
#pragma unroll
            for (int i = 0; i < 4; i++)
#pragma unroll
                for (int j = 0; j < 4; j++)
                    acc[i][j] = __builtin_amdgcn_mfma_f32_16x16x32_bf16(af[i], bfv[j], acc[i][j], 0, 0, 0);
        }
    };
    auto CONVC = [&](const char* A, const char* X, int d) {
#pragma unroll
        for (int ks2 = 0; ks2 < 64; ks2 += 32) {
            int wb = (ks2 >> 3) + (lane >> 4);
            int wa = (wb ^ rx) << 4;
            bf16x8 af[4], bfv[4];
#pragma unroll
            for (int i = 0; i < 4; i++)
                af[i] = *(const bf16x8*)(A + ((wm + i * 16 + lm) << 7) + wa);
#pragma unroll
            for (int j = 0; j < 4; j++) {
                int r2 = wn + j * 16 + lm + d;
                bfv[j] = *(const bf16x8*)(X + (r2 << 7) + ((wb ^ (r2 & 7)) << 4));
            }
#pragma unroll
            for (int i = 0; i < 4; i++)
#pragma unroll
                for (int j = 0; j < 4; j++)
                    acc[i][j] = __builtin_amdgcn_mfma_f32_16x16x32_bf16(af[i], bfv[j], acc[i][j], 0, 0, 0);
        }
    };

    // ---- spectral phase: K=512, 8 steps, dbuf ----
    STAGE_AB(A0, B0, 0);
    __syncthreads();
#pragma unroll
    for (int kp = 0; kp < 4; kp++) {
        int k0 = kp * 128;
        STAGE_AB(A1, B1, k0 + 64);                    // always valid (<=448)
        SPECC(A0, B0);
        __syncthreads();
        if (kp < 3) {
            STAGE_AB(A0, B0, k0 + 128);
        } else {
            STAGE_W(A0, 0, 0);                        // Ws(d=0,c0=0)
            STAGE_X(B0, 0);                           // xT(c0=0) main rows
            EDGE_X(B0, 0);                            // xT halo rows
        }
        SPECC(A1, B1);
        __syncthreads();
    }

    // ---- conv phase: 6 steps (3 taps x 2 ci-halves), dbuf chained ----
    CONVC(A0, B0, 0);  STAGE_W(A1, 1, 0);  STAGE_X(B1, 64);  EDGE_X(B1, 64);
    __syncthreads();
    CONVC(A1, B0, 1);  STAGE_W(A0, 2, 0);
    __syncthreads();
    CONVC(A0, B0, 2);  STAGE_W(A1, 0, 64);
    __syncthreads();
    CONVC(A1, B1, 0);  STAGE_W(A0, 1, 64);
    __syncthreads();
    CONVC(A0, B1, 1);  STAGE_W(A1, 2, 64);
    __syncthreads();
    CONVC(A1, B1, 2);

    // ---- epilogue: blended bias, write-only out ----
    float g = 1.0f / (1.0f + __expf(-gate[0]));
    int q = lane >> 4, cl = lane & 15;
#pragma unroll
    for (int i = 0; i < 4; i++)
#pragma unroll
        for (int j = 0; j < 4; j++) {
            int t = t0 + wn + j * 16 + cl;
#pragma unroll
            for (int r = 0; r < 4; r++) {
                int co = wm + i * 16 + q * 4 + r;
                float gb = g * bias[co] + (1.0f - g) * cb[co];
                out[((size_t)(b * 128 + co) << 14) + t] = acc[i][j][r] + gb;
            }
        }
}

// ---------------- fallback (low-ws) conv + inv, round-1 versions ----------------
#define SA 72
#define SXC 40
__global__ __launch_bounds__(256) void conv_kern(const float* __restrict__ x,
        const __bf16* __restrict__ wbf, const float* __restrict__ cb,
        float* __restrict__ out) {
    __shared__ __align__(16) __bf16 xT[130 * SXC];
    __shared__ __align__(16) __bf16 wS[3 * 128 * SXC];
    int bid = blockIdx.x, b = bid >> 7, t0 = (bid & 127) << 7;
    int tid = threadIdx.x, lane = tid & 63, wv = tid >> 6;
    int wm = (wv >> 1) << 6, wn = (wv & 1) << 6;
    f32x4 acc[4][4] = {};
    for (int c0 = 0; c0 < 128; c0 += 32) {
        for (int idx = tid; idx < 1536; idx += 256) {
            int d = idx / 512, rem = idx - d * 512, co = rem >> 2, g = rem & 3;
            ushort8v v = *(const ushort8v*)(wbf + d * 16384 + co * 128 + c0 + g * 8);
            *(ushort8v*)&wS[d * (128 * SXC) + co * SXC + g * 8] = v;
        }
        for (int idx = tid; idx < 4160; idx += 256) {
            int cc = idx / 130, tl = idx - cc * 130;
            int tg = t0 + tl - 1;
            float v = 0.f;
            if (tg >= 0 && tg < 16384)
                v = x[((size_t)(b * 128 + c0 + cc) << 14) + tg];
            xT[tl * SXC + cc] = (__bf16)v;
        }
        __syncthreads();
        int kf = (lane >> 4) << 3;
#pragma unroll
        for (int d = 0; d < 3; d++) {
            bf16x8 af[4], bfv[4];
#pragma unroll
            for (int i = 0; i < 4; i++)
                af[i] = *(const bf16x8*)&wS[d * (128 * SXC) + (wm + i * 16 + (lane & 15)) * SXC + kf];
#pragma unroll
            for (int j = 0; j < 4; j++)
                bfv[j] = *(const bf16x8*)&xT[(wn + j * 16 + (lane & 15) + d) * SXC + kf];
#pragma unroll
            for (int i = 0; i < 4; i++)
#pragma unroll
                for (int j = 0; j < 4; j++)
                    acc[i][j] = __builtin_amdgcn_mfma_f32_16x16x32_bf16(af[i], bfv[j], acc[i][j], 0, 0, 0);
        }
        __syncthreads();
    }
    int q = lane >> 4, cl = lane & 15;
#pragma unroll
    for (int i = 0; i < 4; i++)
#pragma unroll
        for (int j = 0; j < 4; j++) {
            int t = t0 + wn + j * 16 + cl;
#pragma unroll
            for (int r = 0; r < 4; r++) {
                int co = wm + i * 16 + q * 4 + r;
                out[((size_t)(b * 128 + co) << 14) + t] = acc[i][j][r] + cb[co];
            }
        }
}

__global__ __launch_bounds__(256) void inv_kern(const __bf16* __restrict__ Ob,
        const __bf16* __restrict__ Gtj, const float* __restrict__ bias,
        const float* __restrict__ gate, float* __restrict__ out) {
    __shared__ __align__(16) __bf16 As[128 * SA];
    __shared__ __align__(16) __bf16 Bs[128 * SA];
    int bid = blockIdx.x, mt = bid & 15, tt = bid >> 4;
    int tid = threadIdx.x, lane = tid & 63, wv = tid >> 6;
    int wm = (wv >> 1) << 6, wn = (wv & 1) << 6;
    f32x4 acc[4][4] = {};
    int arow = tid >> 1, ahalf = (tid & 1) << 5;
    const __bf16* ag = Ob  + (size_t)(mt * 128 + arow) * 512 + ahalf;
    const __bf16* bg = Gtj + (size_t)(tt * 128 + arow) * 512 + ahalf;
    __bf16* ad = &As[arow * SA + ahalf];
    __bf16* bd = &Bs[arow * SA + ahalf];
    for (int k0 = 0; k0 < 512; k0 += 64) {
#pragma unroll
        for (int q = 0; q < 4; q++) {
            ((ushort8v*)ad)[q] = ((const ushort8v*)(ag + k0))[q];
            ((ushort8v*)bd)[q] = ((const ushort8v*)(bg + k0))[q];
        }
        __syncthreads();
#pragma unroll
        for (int ks2 = 0; ks2 < 64; ks2 += 32) {
            int kf = ks2 + ((lane >> 4) << 3);
            bf16x8 af[4], bfv[4];
#pragma unroll
            for (int i = 0; i < 4; i++)
                af[i] = *(const bf16x8*)&As[(wm + i * 16 + (lane & 15)) * SA + kf];
#pragma unroll
            for (int j = 0; j < 4; j++)
                bfv[j] = *(const bf16x8*)&Bs[(wn + j * 16 + (lane & 15)) * SA + kf];
#pragma unroll
            for (int i = 0; i < 4; i++)
#pragma unroll
                for (int j = 0; j < 4; j++)
                    acc[i][j] = __builtin_amdgcn_mfma_f32_16x16x32_bf16(af[i], bfv[j], acc[i][j], 0, 0, 0);
        }
        __syncthreads();
    }
    float g = 1.0f / (1.0f + __expf(-gate[0]));
    float gi = 1.0f - g;
    int q = lane >> 4, cl = lane & 15;
#pragma unroll
    for (int i = 0; i < 4; i++)
#pragma unroll
        for (int j = 0; j < 4; j++) {
            int col = (tt << 7) + wn + j * 16 + cl;
#pragma unroll
            for (int r = 0; r < 4; r++) {
                int row = mt * 128 + wm + i * 16 + q * 4 + r;
                size_t oi = ((size_t)row << 14) + col;
                out[oi] = g * (acc[i][j][r] + bias[row & 127]) + gi * out[oi];
            }
        }
}

extern "C" void kernel_launch(void* const* d_in, const int* in_sizes, int n_in,
                              void* d_out, int out_size, void* d_ws, size_t ws_size,
                              hipStream_t stream) {
    const float* x    = (const float*)d_in[0];
    const float* wre  = (const float*)d_in[1];
    const float* wim  = (const float*)d_in[2];
    const float* bias = (const float*)d_in[3];
    const float* cw   = (const float*)d_in[4];
    const float* cb   = (const float*)d_in[5];
    const float* gate = (const float*)d_in[6];
    float* out = (float*)d_out;
    char* ws = (char*)d_ws;

    const size_t SZ_F = 16777216, SZ_G = 16777216, SZ_W = 98304;
    const size_t SZ_X = 67108864, SZ_CP8 = 33554432, SZ_CP4 = 16777216, SZ_OB = 2097152;
    size_t oG = SZ_F, oW = oG + SZ_G, oEnd = oW + SZ_W;   // 33,652,736

    size_t needT3 = oEnd + 2 * SZ_X + SZ_CP8 + SZ_OB;     // 203,522,048
    size_t needT2 = oEnd + SZ_X + SZ_CP8 + SZ_OB;         // 136,413,184
    size_t needT1 = oEnd + SZ_X + SZ_CP4 + SZ_OB;         // 119,635,968

    __bf16* Fjt = (__bf16*)(ws);
    __bf16* Gtj = (__bf16*)(ws + oG);
    __bf16* wbf = (__bf16*)(ws + oW);

    if (ws_size >= needT1) {
        // fused path
        int use_xb = (ws_size >= needT3);
        int ns = (ws_size >= needT2) ? 8 : 4;
        __bf16* xb  = use_xb ? (__bf16*)(ws + oEnd) : nullptr;
        __bf16* xTb = (__bf16*)(ws + oEnd + (use_xb ? SZ_X : 0));
        float*  Cp  = (float*)((char*)xTb + SZ_X);
        __bf16* Ob  = (__bf16*)((char*)Cp + (size_t)ns * 4194304);
        int kchunk = 16384 / ns;

        gen_kern<<<32960, 256, 0, stream>>>(Fjt, Gtj, cw, wbf, gate, 1);
        xpose_kern<<<4096, 256, 0, stream>>>(x, xb, xTb, use_xb);
        if (use_xb)
            fwd_kern<1><<<64 * ns, 256, 65536, stream>>>(x, xb, Fjt, Cp, kchunk);
        else
            fwd_kern<0><<<64 * ns, 256, 32768, stream>>>(x, nullptr, Fjt, Cp, kchunk);
        mix_kern<<<256, 256, 0, stream>>>(Cp, wre, wim, Ob, ns);
        fused_kern<<<2048, 256, 66560, stream>>>(Ob, Gtj, wbf, xTb, bias, cb, gate, out);
    } else {
        // round-1 fallback path
        float*  Cp  = (float*)(ws + oEnd);
        size_t need8 = oEnd + 8ull * 4194304ull + SZ_OB;
        int ns = (ws_size >= need8) ? 8 : 4;
        __bf16* Ob  = (__bf16*)(ws + oEnd + (size_t)ns * 4194304);
        int kchunk = 16384 / ns;

        gen_kern<<<32960, 256, 0, stream>>>(Fjt, Gtj, cw, wbf, gate, 0);
        fwd_kern<0><<<64 * ns, 256, 32768, stream>>>(x, nullptr, Fjt, Cp, kchunk);
        mix_kern<<<256, 256, 0, stream>>>(Cp, wre, wim, Ob, ns);
        conv_kern<<<2048, 256, 0, stream>>>(x, wbf, cb, out);
        inv_kern<<<2048, 256, 0, stream>>>(Ob, Gtj, bias, gate, out);
    }
}